// Round 1
// baseline (866.692 us; speedup 1.0000x reference)
//
#include <hip/hip_runtime.h>
#include <hip/hip_bf16.h>
#include <cstdint>
#include <cstddef>

typedef __bf16 bf16;
typedef __bf16 bf16x8 __attribute__((ext_vector_type(8)));
typedef float f32x4 __attribute__((ext_vector_type(4)));

#define D_MODEL 2048
#define SEQ     2048
#define NH      16
#define HD      128
#define BATCH   2

// ---------------- async global->LDS 16B ----------------
__device__ __forceinline__ void gld16(void* lds, const void* g) {
    __builtin_amdgcn_global_load_lds(
        (const __attribute__((address_space(1))) unsigned int*)g,
        (__attribute__((address_space(3))) unsigned int*)lds,
        16, 0, 0);
}

// ---------------- fp32 -> bf16 convert ----------------
__global__ __launch_bounds__(256) void cvt_f32_bf16(const float* __restrict__ in,
                                                    bf16* __restrict__ out, int n) {
    int i = (blockIdx.x * 256 + threadIdx.x) * 4;
    if (i < n) {
        float4 v = *(const float4*)(in + i);
        out[i + 0] = (bf16)v.x;
        out[i + 1] = (bf16)v.y;
        out[i + 2] = (bf16)v.z;
        out[i + 3] = (bf16)v.w;
    }
}

// ---------------- RoPE tables (cos/sin, S x 64) ----------------
__global__ __launch_bounds__(256) void rope_tables_k(float* __restrict__ cosd,
                                                     float* __restrict__ sind) {
    int id = blockIdx.x * 256 + threadIdx.x;  // SEQ*64
    int s = id >> 6, d = id & 63;
    float freq = powf(10000.f, -(float)d * (1.f / 64.f));
    float a = (float)s * freq;
    float sn, c;
    sincosf(a, &sn, &c);
    cosd[id] = c;
    sind[id] = sn;
}

// ---------------- RoPE apply (in-place on bf16 [B*S][2048]) ----------------
__global__ __launch_bounds__(256) void rope_apply(bf16* __restrict__ T,
                                                  const float* __restrict__ cosd,
                                                  const float* __restrict__ sind,
                                                  float scale) {
    int id = blockIdx.x * 256 + threadIdx.x;   // B*S*NH*64
    int row = id >> 10;                        // B*S
    int p = id & 1023;
    int h = p >> 6, d = p & 63;
    int s = row & (SEQ - 1);
    size_t base = (size_t)row * D_MODEL + h * HD + d;
    float x1 = (float)T[base];
    float x2 = (float)T[base + 64];
    float c = cosd[(s << 6) + d];
    float sn = sind[(s << 6) + d];
    T[base]      = (bf16)((x1 * c - x2 * sn) * scale);
    T[base + 64] = (bf16)((x2 * c + x1 * sn) * scale);
}

// ---------------- V transpose: [B,S,H*D] -> [B,H,D,S] ----------------
__global__ __launch_bounds__(256) void transpose_v(const bf16* __restrict__ V,
                                                   bf16* __restrict__ Vt) {
    __shared__ bf16 t[32][33];
    int s0 = blockIdx.x * 32;
    int d0 = blockIdx.y * 32;
    int bh = blockIdx.z;
    int b = bh >> 4, h = bh & 15;
    int tx = threadIdx.x & 31, ty = threadIdx.x >> 5;  // ty 0..7
#pragma unroll
    for (int i = 0; i < 32; i += 8)
        t[ty + i][tx] = V[((size_t)(b * SEQ + s0 + ty + i)) * D_MODEL + h * HD + d0 + tx];
    __syncthreads();
#pragma unroll
    for (int i = 0; i < 32; i += 8)
        Vt[((size_t)bh * HD + d0 + ty + i) * SEQ + s0 + tx] = t[tx][ty + i];
}

// ---------------- NT GEMM: C[M,N] = A[M,K] * B[N,K]^T, bf16 in, bf16/f32 out ----
// 128x128 tile, BK=32, 256 threads (4 waves 2x2), double-buffered LDS via
// global_load_lds width-16.
template <int OUTF32>
__global__ __launch_bounds__(256)
void gemm_nt(const bf16* __restrict__ A, const bf16* __restrict__ B,
             void* __restrict__ Cout, int M, int N, int K) {
    __shared__ bf16 As[2][128 * 32];
    __shared__ bf16 Bs[2][128 * 32];
    const int m0 = blockIdx.y * 128, n0 = blockIdx.x * 128;
    const int tid = threadIdx.x;
    const int w = tid >> 6, l = tid & 63;
    const int wr = w >> 1, wc = w & 1;
    const int lg = l >> 4, lc = l & 15;

    f32x4 acc[4][4] = {};
    const int NT = K >> 5;

    auto stage = [&](int p, int t) {
#pragma unroll
        for (int c = 0; c < 2; ++c) {
            int reg = w * 2 + c;
            const bf16* ga = A + (size_t)(m0 + reg * 16 + (l >> 2)) * K + t * 32 + (l & 3) * 8;
            const bf16* gb = B + (size_t)(n0 + reg * 16 + (l >> 2)) * K + t * 32 + (l & 3) * 8;
            gld16(&As[p][reg * 512], ga);
            gld16(&Bs[p][reg * 512], gb);
        }
    };

    stage(0, 0);
    int cur = 0;
    for (int t = 0; t < NT; ++t) {
        __syncthreads();               // drains vmcnt: buf[cur] ready; prev reads done
        if (t + 1 < NT) stage(cur ^ 1, t + 1);
        bf16x8 af[4], bfr[4];
#pragma unroll
        for (int m = 0; m < 4; ++m)
            af[m] = *(const bf16x8*)&As[cur][(wr * 64 + m * 16 + lc) * 32 + lg * 8];
#pragma unroll
        for (int n = 0; n < 4; ++n)
            bfr[n] = *(const bf16x8*)&Bs[cur][(wc * 64 + n * 16 + lc) * 32 + lg * 8];
#pragma unroll
        for (int m = 0; m < 4; ++m)
#pragma unroll
            for (int n = 0; n < 4; ++n)
                acc[m][n] = __builtin_amdgcn_mfma_f32_16x16x32_bf16(af[m], bfr[n], acc[m][n], 0, 0, 0);
        cur ^= 1;
    }

#pragma unroll
    for (int m = 0; m < 4; ++m)
#pragma unroll
        for (int n = 0; n < 4; ++n)
#pragma unroll
            for (int r = 0; r < 4; ++r) {
                size_t row = (size_t)m0 + wr * 64 + m * 16 + lg * 4 + r;
                size_t col = (size_t)n0 + wc * 64 + n * 16 + lc;
                float v = acc[m][n][r];
                if (OUTF32)
                    ((float*)Cout)[row * N + col] = v;
                else
                    ((bf16*)Cout)[row * N + col] = (bf16)v;
            }
}

// ---------------- Flash attention (causal) ----------------
// grid (S/64, B*H), 256 threads = 4 waves, 16 q-rows per wave.
// Q,K: [B,S,H*D] bf16 (Q pre-scaled by 1/sqrt(D)); Vt: [B,H,D,S]; O: [B,S,H*D].
__global__ __launch_bounds__(256)
void flash_attn(const bf16* __restrict__ Q, const bf16* __restrict__ K,
                const bf16* __restrict__ Vt, bf16* __restrict__ O) {
    __shared__ bf16 p_lds[4][16][64];
    const int qb = blockIdx.x, bh = blockIdx.y;
    const int b = bh >> 4, h = bh & 15;
    const int w = threadIdx.x >> 6, l = threadIdx.x & 63;
    const int lg = l >> 4, lc = l & 15;
    const int q0 = qb * 64 + w * 16;

    // Q fragments (A-layout: row=lc, k contiguous 8 at lg*8)
    const bf16* qp = Q + ((size_t)(b * SEQ + q0 + lc)) * D_MODEL + h * HD + lg * 8;
    bf16x8 qf[4];
#pragma unroll
    for (int kc = 0; kc < 4; ++kc) qf[kc] = *(const bf16x8*)(qp + kc * 32);

    f32x4 ctx[8] = {};
    float mrun[4], lrun[4];
#pragma unroll
    for (int r = 0; r < 4; ++r) { mrun[r] = -INFINITY; lrun[r] = 0.f; }

    for (int kb = 0; kb <= qb; ++kb) {
        // ---- S = Q K^T over 64-key block ----
        f32x4 sacc[4] = {};
        const bf16* kp = K + ((size_t)(b * SEQ + kb * 64 + lc)) * D_MODEL + h * HD + lg * 8;
#pragma unroll
        for (int nf = 0; nf < 4; ++nf)
#pragma unroll
            for (int kc = 0; kc < 4; ++kc) {
                bf16x8 kf = *(const bf16x8*)(kp + (size_t)nf * 16 * D_MODEL + kc * 32);
                sacc[nf] = __builtin_amdgcn_mfma_f32_16x16x32_bf16(qf[kc], kf, sacc[nf], 0, 0, 0);
            }

        // causal mask on diagonal block
        if (kb == qb) {
#pragma unroll
            for (int nf = 0; nf < 4; ++nf) {
                int key = kb * 64 + nf * 16 + lc;
#pragma unroll
                for (int r = 0; r < 4; ++r)
                    if (key > q0 + lg * 4 + r) sacc[nf][r] = -INFINITY;
            }
        }

        // ---- online softmax (rows live on 16-lane groups) ----
        float scv[4], rs[4];
#pragma unroll
        for (int r = 0; r < 4; ++r) {
            float mx = fmaxf(fmaxf(sacc[0][r], sacc[1][r]), fmaxf(sacc[2][r], sacc[3][r]));
#pragma unroll
            for (int off = 1; off < 16; off <<= 1) mx = fmaxf(mx, __shfl_xor(mx, off));
            float mi = fmaxf(mrun[r], mx);
            scv[r] = __expf(mrun[r] - mi);
            mrun[r] = mi;
            rs[r] = 0.f;
        }
#pragma unroll
        for (int nf = 0; nf < 4; ++nf)
#pragma unroll
            for (int r = 0; r < 4; ++r) {
                float p = __expf(sacc[nf][r] - mrun[r]);
                rs[r] += p;
                p_lds[w][lg * 4 + r][nf * 16 + lc] = (bf16)p;
            }
#pragma unroll
        for (int r = 0; r < 4; ++r) {
#pragma unroll
            for (int off = 1; off < 16; off <<= 1) rs[r] += __shfl_xor(rs[r], off);
            lrun[r] = lrun[r] * scv[r] + rs[r];
        }
#pragma unroll
        for (int nd = 0; nd < 8; ++nd)
#pragma unroll
            for (int r = 0; r < 4; ++r) ctx[nd][r] *= scv[r];

        // make the cross-lane LDS writes visible to this wave's reads
        asm volatile("s_waitcnt lgkmcnt(0)" ::: "memory");
        bf16x8 pa0 = *(const bf16x8*)&p_lds[w][lc][lg * 8];
        bf16x8 pa1 = *(const bf16x8*)&p_lds[w][lc][32 + lg * 8];

        // ---- ctx += P V (Vt rows are d, contiguous keys) ----
        const bf16* vp = Vt + ((size_t)bh * HD + lc) * SEQ + kb * 64 + lg * 8;
#pragma unroll
        for (int nd = 0; nd < 8; ++nd) {
#pragma unroll
            for (int k2 = 0; k2 < 2; ++k2) {
                bf16x8 vf = *(const bf16x8*)(vp + (size_t)nd * 16 * SEQ + k2 * 32);
                ctx[nd] = __builtin_amdgcn_mfma_f32_16x16x32_bf16(k2 ? pa1 : pa0, vf, ctx[nd], 0, 0, 0);
            }
        }
    }

#pragma unroll
    for (int r = 0; r < 4; ++r) lrun[r] = 1.f / lrun[r];
#pragma unroll
    for (int nd = 0; nd < 8; ++nd)
#pragma unroll
        for (int r = 0; r < 4; ++r)
            O[((size_t)(b * SEQ + q0 + lg * 4 + r)) * D_MODEL + h * HD + nd * 16 + lc] =
                (bf16)(ctx[nd][r] * lrun[r]);
}

// ---------------- launch ----------------
extern "C" void kernel_launch(void* const* d_in, const int* in_sizes, int n_in,
                              void* d_out, int out_size, void* d_ws, size_t ws_size,
                              hipStream_t stream) {
    const float* x  = (const float*)d_in[0];
    const float* Wq = (const float*)d_in[1];
    const float* Wk = (const float*)d_in[2];
    const float* Wv = (const float*)d_in[3];
    const float* Wo = (const float*)d_in[4];

    char* ws = (char*)d_ws;
    bf16* xb  = (bf16*)(ws + 0);
    bf16* wqb = (bf16*)(ws + 16777216);
    bf16* wkb = (bf16*)(ws + 25165824);
    bf16* wvb = (bf16*)(ws + 33554432);
    bf16* wob = (bf16*)(ws + 41943040);
    bf16* Qb  = (bf16*)(ws + 50331648);
    bf16* Kb  = (bf16*)(ws + 67108864);
    bf16* Vb  = (bf16*)(ws + 83886080);   // later reused as ctx
    bf16* Vtb = (bf16*)(ws + 100663296);
    float* cosd = (float*)(ws + 117440512);
    float* sind = (float*)(ws + 117964800);

    const int NX = BATCH * SEQ * D_MODEL;   // 8388608
    const int NW = D_MODEL * D_MODEL;       // 4194304

    cvt_f32_bf16<<<NX / 1024, 256, 0, stream>>>(x,  xb,  NX);
    cvt_f32_bf16<<<NW / 1024, 256, 0, stream>>>(Wq, wqb, NW);
    cvt_f32_bf16<<<NW / 1024, 256, 0, stream>>>(Wk, wkb, NW);
    cvt_f32_bf16<<<NW / 1024, 256, 0, stream>>>(Wv, wvb, NW);
    cvt_f32_bf16<<<NW / 1024, 256, 0, stream>>>(Wo, wob, NW);

    rope_tables_k<<<(SEQ * 64) / 256, 256, 0, stream>>>(cosd, sind);

    dim3 ggrid(D_MODEL / 128, (BATCH * SEQ) / 128);  // (16, 32)
    gemm_nt<0><<<ggrid, 256, 0, stream>>>(xb, wqb, Qb, BATCH * SEQ, D_MODEL, D_MODEL);
    gemm_nt<0><<<ggrid, 256, 0, stream>>>(xb, wkb, Kb, BATCH * SEQ, D_MODEL, D_MODEL);
    gemm_nt<0><<<ggrid, 256, 0, stream>>>(xb, wvb, Vb, BATCH * SEQ, D_MODEL, D_MODEL);

    const float qscale = 0.08838834764831845f;  // 1/sqrt(128)
    rope_apply<<<(BATCH * SEQ * 1024) / 256, 256, 0, stream>>>(Qb, cosd, sind, qscale);
    rope_apply<<<(BATCH * SEQ * 1024) / 256, 256, 0, stream>>>(Kb, cosd, sind, 1.0f);

    transpose_v<<<dim3(SEQ / 32, HD / 32, BATCH * NH), 256, 0, stream>>>(Vb, Vtb);

    flash_attn<<<dim3(SEQ / 64, BATCH * NH), 256, 0, stream>>>(Qb, Kb, Vtb, Vb /*ctx*/);

    gemm_nt<1><<<ggrid, 256, 0, stream>>>(Vb /*ctx*/, wob, d_out, BATCH * SEQ, D_MODEL, D_MODEL);
}

// Round 2
// 373.592 us; speedup vs baseline: 2.3199x; 2.3199x over previous
//
#include <hip/hip_runtime.h>
#include <hip/hip_bf16.h>
#include <cstdint>
#include <cstddef>

typedef __bf16 bf16;
typedef __bf16 bf16x8 __attribute__((ext_vector_type(8)));
typedef float f32x4 __attribute__((ext_vector_type(4)));

#define D_MODEL 2048
#define SEQ     2048
#define NH      16
#define HD      128
#define BATCH   2

// ---------------- async global->LDS 16B ----------------
__device__ __forceinline__ void gld16(void* lds, const void* g) {
    __builtin_amdgcn_global_load_lds(
        (const __attribute__((address_space(1))) unsigned int*)g,
        (__attribute__((address_space(3))) unsigned int*)lds,
        16, 0, 0);
}

// ---------------- fp32 -> bf16 convert ----------------
__global__ __launch_bounds__(256) void cvt_f32_bf16(const float* __restrict__ in,
                                                    bf16* __restrict__ out, int n) {
    int i = (blockIdx.x * 256 + threadIdx.x) * 4;
    if (i < n) {
        float4 v = *(const float4*)(in + i);
        out[i + 0] = (bf16)v.x;
        out[i + 1] = (bf16)v.y;
        out[i + 2] = (bf16)v.z;
        out[i + 3] = (bf16)v.w;
    }
}

// ---------------- RoPE tables (cos/sin, S x 64) ----------------
__global__ __launch_bounds__(256) void rope_tables_k(float* __restrict__ cosd,
                                                     float* __restrict__ sind) {
    int id = blockIdx.x * 256 + threadIdx.x;  // SEQ*64
    int s = id >> 6, d = id & 63;
    float freq = powf(10000.f, -(float)d * (1.f / 64.f));
    float a = (float)s * freq;
    float sn, c;
    sincosf(a, &sn, &c);
    cosd[id] = c;
    sind[id] = sn;
}

// ---------------- RoPE apply (in-place on bf16 [B*S][2048]) ----------------
__global__ __launch_bounds__(256) void rope_apply(bf16* __restrict__ T,
                                                  const float* __restrict__ cosd,
                                                  const float* __restrict__ sind,
                                                  float scale) {
    int id = blockIdx.x * 256 + threadIdx.x;   // B*S*NH*64
    int row = id >> 10;                        // B*S
    int p = id & 1023;
    int h = p >> 6, d = p & 63;
    int s = row & (SEQ - 1);
    size_t base = (size_t)row * D_MODEL + h * HD + d;
    float x1 = (float)T[base];
    float x2 = (float)T[base + 64];
    float c = cosd[(s << 6) + d];
    float sn = sind[(s << 6) + d];
    T[base]      = (bf16)((x1 * c - x2 * sn) * scale);
    T[base + 64] = (bf16)((x2 * c + x1 * sn) * scale);
}

// ---------------- V transpose: [B,S,H*D] -> [B,H,D,S] ----------------
__global__ __launch_bounds__(256) void transpose_v(const bf16* __restrict__ V,
                                                   bf16* __restrict__ Vt) {
    __shared__ bf16 t[32][33];
    int s0 = blockIdx.x * 32;
    int d0 = blockIdx.y * 32;
    int bh = blockIdx.z;
    int b = bh >> 4, h = bh & 15;
    int tx = threadIdx.x & 31, ty = threadIdx.x >> 5;  // ty 0..7
#pragma unroll
    for (int i = 0; i < 32; i += 8)
        t[ty + i][tx] = V[((size_t)(b * SEQ + s0 + ty + i)) * D_MODEL + h * HD + d0 + tx];
    __syncthreads();
#pragma unroll
    for (int i = 0; i < 32; i += 8)
        Vt[((size_t)bh * HD + d0 + ty + i) * SEQ + s0 + tx] = t[tx][ty + i];
}

// ---------------- NT GEMM: C[M,N] = A[M,K] * B[N,K]^T ----
template <int OUTF32>
__global__ __launch_bounds__(256)
void gemm_nt(const bf16* __restrict__ A, const bf16* __restrict__ B,
             void* __restrict__ Cout, int M, int N, int K) {
    __shared__ bf16 As[2][128 * 32];
    __shared__ bf16 Bs[2][128 * 32];
    const int m0 = blockIdx.y * 128, n0 = blockIdx.x * 128;
    const int tid = threadIdx.x;
    const int w = tid >> 6, l = tid & 63;
    const int wr = w >> 1, wc = w & 1;
    const int lg = l >> 4, lc = l & 15;

    f32x4 acc[4][4] = {};
    const int NT = K >> 5;

    auto stage = [&](int p, int t) {
#pragma unroll
        for (int c = 0; c < 2; ++c) {
            int reg = w * 2 + c;
            const bf16* ga = A + (size_t)(m0 + reg * 16 + (l >> 2)) * K + t * 32 + (l & 3) * 8;
            const bf16* gb = B + (size_t)(n0 + reg * 16 + (l >> 2)) * K + t * 32 + (l & 3) * 8;
            gld16(&As[p][reg * 512], ga);
            gld16(&Bs[p][reg * 512], gb);
        }
    };

    stage(0, 0);
    int cur = 0;
    for (int t = 0; t < NT; ++t) {
        __syncthreads();
        if (t + 1 < NT) stage(cur ^ 1, t + 1);
        bf16x8 af[4], bfr[4];
#pragma unroll
        for (int m = 0; m < 4; ++m)
            af[m] = *(const bf16x8*)&As[cur][(wr * 64 + m * 16 + lc) * 32 + lg * 8];
#pragma unroll
        for (int n = 0; n < 4; ++n)
            bfr[n] = *(const bf16x8*)&Bs[cur][(wc * 64 + n * 16 + lc) * 32 + lg * 8];
#pragma unroll
        for (int m = 0; m < 4; ++m)
#pragma unroll
            for (int n = 0; n < 4; ++n)
                acc[m][n] = __builtin_amdgcn_mfma_f32_16x16x32_bf16(af[m], bfr[n], acc[m][n], 0, 0, 0);
        cur ^= 1;
    }

#pragma unroll
    for (int m = 0; m < 4; ++m)
#pragma unroll
        for (int n = 0; n < 4; ++n)
#pragma unroll
            for (int r = 0; r < 4; ++r) {
                size_t row = (size_t)m0 + wr * 64 + m * 16 + lg * 4 + r;
                size_t col = (size_t)n0 + wc * 64 + n * 16 + lc;
                float v = acc[m][n][r];
                if (OUTF32)
                    ((float*)Cout)[row * N + col] = v;
                else
                    ((bf16*)Cout)[row * N + col] = (bf16)v;
            }
}

// ---------------- Flash attention (causal), LDS-staged ----------------
// grid 1024 linear; per block: 256 thr = 4 waves, 64 q-rows (16/wave), KV tiles
// of 64 keys staged double-buffered in LDS via global_load_lds, XOR-swizzled.
__global__ __launch_bounds__(256)
void flash_attn(const bf16* __restrict__ Q, const bf16* __restrict__ K,
                const bf16* __restrict__ Vt, bf16* __restrict__ O) {
    __shared__ __align__(16) bf16 Ks[2][64 * 128];   // [key][d], rows 256B
    __shared__ __align__(16) bf16 Vs[2][128 * 64];   // [d][key], rows 128B
    __shared__ __align__(16) bf16 p_lds[4][16 * 64]; // per-wave P, rows 128B

    // XCD-chunked + LPT mapping: 8 XCDs x 128 blocks; within an XCD,
    // slots ascend over (bh, qb-descending) so long blocks start first.
    const int hw = blockIdx.x;
    const int lin = (hw & 7) * 128 + (hw >> 3);
    const int bh = lin >> 5;
    const int qb = 31 - (lin & 31);
    const int b = bh >> 4, h = bh & 15;

    const int tid = threadIdx.x;
    const int w = tid >> 6, l = tid & 63;
    const int lg = l >> 4, lc = l & 15;
    const int q0 = qb * 64 + w * 16;

    auto stageK = [&](int p, int kb) {
#pragma unroll
        for (int c = 0; c < 4; ++c) {
            int r = c * 16 + w * 4 + (l >> 4);
            int scb = ((l & 15) * 16) ^ ((r & 7) << 4);  // pre-swizzled src col byte
            const bf16* g = K + ((size_t)(b * SEQ + kb * 64 + r)) * D_MODEL + h * HD + (scb >> 1);
            gld16(&Ks[p][(c * 16 + w * 4) * 128], g);
        }
    };
    auto stageV = [&](int p, int kb) {
#pragma unroll
        for (int c = 0; c < 4; ++c) {
            int r = c * 32 + w * 8 + (l >> 3);
            int scb = ((l & 7) * 16) ^ ((r & 7) << 4);
            const bf16* g = Vt + ((size_t)bh * HD + r) * SEQ + kb * 64 + (scb >> 1);
            gld16(&Vs[p][(c * 32 + w * 8) * 64], g);
        }
    };

    // Q fragments (A-layout: row=lc, 8 contiguous k at lg*8)
    const bf16* qp = Q + ((size_t)(b * SEQ + q0 + lc)) * D_MODEL + h * HD + lg * 8;
    bf16x8 qf[4];
#pragma unroll
    for (int kc = 0; kc < 4; ++kc) qf[kc] = *(const bf16x8*)(qp + kc * 32);

    f32x4 ctx[8] = {};
    float mrun[4], lrun[4];
#pragma unroll
    for (int r = 0; r < 4; ++r) { mrun[r] = -INFINITY; lrun[r] = 0.f; }

    stageK(0, 0);
    stageV(0, 0);
    int cur = 0;
    const int kswz = (lc & 7) << 4;
    char* pb = (char*)&p_lds[w][0];

    for (int kb = 0; kb <= qb; ++kb) {
        __syncthreads();  // buf[cur] staged (vmcnt drained); prev reads done
        if (kb < qb) { stageK(cur ^ 1, kb + 1); stageV(cur ^ 1, kb + 1); }

        // ---- S = Q K^T ----
        const char* kbp = (const char*)&Ks[cur][0];
        f32x4 sacc[4] = {};
#pragma unroll
        for (int nf = 0; nf < 4; ++nf) {
            int krow = nf * 16 + lc;
#pragma unroll
            for (int kc = 0; kc < 4; ++kc) {
                bf16x8 kf = *(const bf16x8*)(kbp + krow * 256 + ((kc * 64 + lg * 16) ^ kswz));
                sacc[nf] = __builtin_amdgcn_mfma_f32_16x16x32_bf16(qf[kc], kf, sacc[nf], 0, 0, 0);
            }
        }

        if (kb == qb) {  // causal mask on diagonal block
#pragma unroll
            for (int nf = 0; nf < 4; ++nf) {
                int key = kb * 64 + nf * 16 + lc;
#pragma unroll
                for (int r = 0; r < 4; ++r)
                    if (key > q0 + lg * 4 + r) sacc[nf][r] = -INFINITY;
            }
        }

        // ---- online softmax (rows on 16-lane groups) ----
        float scv[4], rs[4];
#pragma unroll
        for (int r = 0; r < 4; ++r) {
            float mx = fmaxf(fmaxf(sacc[0][r], sacc[1][r]), fmaxf(sacc[2][r], sacc[3][r]));
#pragma unroll
            for (int off = 1; off < 16; off <<= 1) mx = fmaxf(mx, __shfl_xor(mx, off));
            float mi = fmaxf(mrun[r], mx);
            scv[r] = __expf(mrun[r] - mi);
            mrun[r] = mi;
            rs[r] = 0.f;
        }
#pragma unroll
        for (int nf = 0; nf < 4; ++nf)
#pragma unroll
            for (int r = 0; r < 4; ++r) {
                float p = __expf(sacc[nf][r] - mrun[r]);
                rs[r] += p;
                int pr = lg * 4 + r;
                int pcb = (nf * 16 + lc) * 2;
                *(bf16*)(pb + pr * 128 + (pcb ^ ((pr & 7) << 4))) = (bf16)p;
            }
#pragma unroll
        for (int r = 0; r < 4; ++r) {
#pragma unroll
            for (int off = 1; off < 16; off <<= 1) rs[r] += __shfl_xor(rs[r], off);
            lrun[r] = lrun[r] * scv[r] + rs[r];
        }
#pragma unroll
        for (int nd = 0; nd < 8; ++nd)
#pragma unroll
            for (int r = 0; r < 4; ++r) ctx[nd][r] *= scv[r];

        // cross-lane LDS P writes -> visible to this wave's reads
        asm volatile("s_waitcnt lgkmcnt(0)" ::: "memory");
        bf16x8 pa0 = *(const bf16x8*)(pb + lc * 128 + ((lg * 16) ^ kswz));
        bf16x8 pa1 = *(const bf16x8*)(pb + lc * 128 + ((64 + lg * 16) ^ kswz));

        // ---- ctx += P V ----
        const char* vb = (const char*)&Vs[cur][0];
#pragma unroll
        for (int nd = 0; nd < 8; ++nd) {
            int vrow = nd * 16 + lc;
#pragma unroll
            for (int k2 = 0; k2 < 2; ++k2) {
                bf16x8 vf = *(const bf16x8*)(vb + vrow * 128 + ((k2 * 64 + lg * 16) ^ kswz));
                ctx[nd] = __builtin_amdgcn_mfma_f32_16x16x32_bf16(k2 ? pa1 : pa0, vf, ctx[nd], 0, 0, 0);
            }
        }
        cur ^= 1;
    }

#pragma unroll
    for (int r = 0; r < 4; ++r) lrun[r] = 1.f / lrun[r];
#pragma unroll
    for (int nd = 0; nd < 8; ++nd)
#pragma unroll
        for (int r = 0; r < 4; ++r)
            O[((size_t)(b * SEQ + q0 + lg * 4 + r)) * D_MODEL + h * HD + nd * 16 + lc] =
                (bf16)(ctx[nd][r] * lrun[r]);
}

// ---------------- launch ----------------
extern "C" void kernel_launch(void* const* d_in, const int* in_sizes, int n_in,
                              void* d_out, int out_size, void* d_ws, size_t ws_size,
                              hipStream_t stream) {
    const float* x  = (const float*)d_in[0];
    const float* Wq = (const float*)d_in[1];
    const float* Wk = (const float*)d_in[2];
    const float* Wv = (const float*)d_in[3];
    const float* Wo = (const float*)d_in[4];

    char* ws = (char*)d_ws;
    bf16* xb  = (bf16*)(ws + 0);
    bf16* wqb = (bf16*)(ws + 16777216);
    bf16* wkb = (bf16*)(ws + 25165824);
    bf16* wvb = (bf16*)(ws + 33554432);
    bf16* wob = (bf16*)(ws + 41943040);
    bf16* Qb  = (bf16*)(ws + 50331648);
    bf16* Kb  = (bf16*)(ws + 67108864);
    bf16* Vb  = (bf16*)(ws + 83886080);   // later reused as ctx
    bf16* Vtb = (bf16*)(ws + 100663296);
    float* cosd = (float*)(ws + 117440512);
    float* sind = (float*)(ws + 117964800);

    const int NX = BATCH * SEQ * D_MODEL;   // 8388608
    const int NW = D_MODEL * D_MODEL;       // 4194304

    cvt_f32_bf16<<<NX / 1024, 256, 0, stream>>>(x,  xb,  NX);
    cvt_f32_bf16<<<NW / 1024, 256, 0, stream>>>(Wq, wqb, NW);
    cvt_f32_bf16<<<NW / 1024, 256, 0, stream>>>(Wk, wkb, NW);
    cvt_f32_bf16<<<NW / 1024, 256, 0, stream>>>(Wv, wvb, NW);
    cvt_f32_bf16<<<NW / 1024, 256, 0, stream>>>(Wo, wob, NW);

    rope_tables_k<<<(SEQ * 64) / 256, 256, 0, stream>>>(cosd, sind);

    dim3 ggrid(D_MODEL / 128, (BATCH * SEQ) / 128);  // (16, 32)
    gemm_nt<0><<<ggrid, 256, 0, stream>>>(xb, wqb, Qb, BATCH * SEQ, D_MODEL, D_MODEL);
    gemm_nt<0><<<ggrid, 256, 0, stream>>>(xb, wkb, Kb, BATCH * SEQ, D_MODEL, D_MODEL);
    gemm_nt<0><<<ggrid, 256, 0, stream>>>(xb, wvb, Vb, BATCH * SEQ, D_MODEL, D_MODEL);

    const float qscale = 0.08838834764831845f;  // 1/sqrt(128)
    rope_apply<<<(BATCH * SEQ * 1024) / 256, 256, 0, stream>>>(Qb, cosd, sind, qscale);
    rope_apply<<<(BATCH * SEQ * 1024) / 256, 256, 0, stream>>>(Kb, cosd, sind, 1.0f);

    transpose_v<<<dim3(SEQ / 32, HD / 32, BATCH * NH), 256, 0, stream>>>(Vb, Vtb);

    flash_attn<<<dim3(1024), 256, 0, stream>>>(Qb, Kb, Vtb, Vb /*ctx*/);

    gemm_nt<1><<<ggrid, 256, 0, stream>>>(Vb /*ctx*/, wob, d_out, BATCH * SEQ, D_MODEL, D_MODEL);
}

// Round 3
// 349.244 us; speedup vs baseline: 2.4816x; 1.0697x over previous
//
#include <hip/hip_runtime.h>
#include <hip/hip_bf16.h>
#include <cstdint>
#include <cstddef>

typedef __bf16 bf16;
typedef __bf16 bf16x8 __attribute__((ext_vector_type(8)));
typedef float f32x4 __attribute__((ext_vector_type(4)));

#define D_MODEL 2048
#define SEQ     2048
#define NH      16
#define HD      128
#define BATCH   2
#define QKV_LD  6144

#define SBAR()  __builtin_amdgcn_sched_barrier(0)
#define HWBAR() do { SBAR(); __builtin_amdgcn_s_barrier(); SBAR(); } while (0)

// ---------------- async global->LDS 16B ----------------
__device__ __forceinline__ void gld16(void* lds, const void* g) {
    __builtin_amdgcn_global_load_lds(
        (const __attribute__((address_space(1))) unsigned int*)g,
        (__attribute__((address_space(3))) unsigned int*)lds,
        16, 0, 0);
}

// ---------------- fp32 -> bf16 convert ----------------
__global__ __launch_bounds__(256) void cvt_f32_bf16(const float* __restrict__ in,
                                                    bf16* __restrict__ out, int n) {
    int i = (blockIdx.x * 256 + threadIdx.x) * 4;
    if (i < n) {
        float4 v = *(const float4*)(in + i);
        out[i + 0] = (bf16)v.x;
        out[i + 1] = (bf16)v.y;
        out[i + 2] = (bf16)v.z;
        out[i + 3] = (bf16)v.w;
    }
}

// ---------------- RoPE tables (cos/sin, S x 64) ----------------
__global__ __launch_bounds__(256) void rope_tables_k(float* __restrict__ cosd,
                                                     float* __restrict__ sind) {
    int id = blockIdx.x * 256 + threadIdx.x;  // SEQ*64
    int s = id >> 6, d = id & 63;
    float freq = powf(10000.f, -(float)d * (1.f / 64.f));
    float a = (float)s * freq;
    float sn, c;
    sincosf(a, &sn, &c);
    cosd[id] = c;
    sind[id] = sn;
}

// ---------------- RoPE apply (in-place, row stride ld) ----------------
__global__ __launch_bounds__(256) void rope_apply(bf16* __restrict__ T,
                                                  const float* __restrict__ cosd,
                                                  const float* __restrict__ sind,
                                                  float scale, int ld) {
    int id = blockIdx.x * 256 + threadIdx.x;   // B*S*NH*64
    int row = id >> 10;                        // B*S
    int p = id & 1023;
    int h = p >> 6, d = p & 63;
    int s = row & (SEQ - 1);
    size_t base = (size_t)row * ld + h * HD + d;
    float x1 = (float)T[base];
    float x2 = (float)T[base + 64];
    float c = cosd[(s << 6) + d];
    float sn = sind[(s << 6) + d];
    T[base]      = (bf16)((x1 * c - x2 * sn) * scale);
    T[base + 64] = (bf16)((x2 * c + x1 * sn) * scale);
}

// ---------------- V transpose: [B,S,(ld)] head cols -> [B,H,D,S] ----------------
__global__ __launch_bounds__(256) void transpose_v(const bf16* __restrict__ V,
                                                   bf16* __restrict__ Vt, int ld) {
    __shared__ bf16 t[32][33];
    int s0 = blockIdx.x * 32;
    int d0 = blockIdx.y * 32;
    int bh = blockIdx.z;
    int b = bh >> 4, h = bh & 15;
    int tx = threadIdx.x & 31, ty = threadIdx.x >> 5;  // ty 0..7
#pragma unroll
    for (int i = 0; i < 32; i += 8)
        t[ty + i][tx] = V[((size_t)(b * SEQ + s0 + ty + i)) * ld + h * HD + d0 + tx];
    __syncthreads();
#pragma unroll
    for (int i = 0; i < 32; i += 8)
        Vt[((size_t)bh * HD + d0 + ty + i) * SEQ + s0 + tx] = t[tx][ty + i];
}

// ---------------- 256x256 8-phase NT GEMM ----------------
// C[M,N] = A[M,K] * B[N,K]^T. 512 thr = 8 waves (2M x 4N), BK=64,
// double-buffered 128 KiB LDS, row-XOR swizzle, counted vmcnt, setprio.
template <int OUTF32>
__global__ __launch_bounds__(512, 2)
void gemm8p(const bf16* __restrict__ A, const bf16* __restrict__ B,
            void* __restrict__ Cout, int M, int N, int K) {
    // [buf][mat A0/B1][half][128 rows * 64 cols]
    __shared__ __align__(16) bf16 ldsAB[2][2][2][128 * 64];

    const int nN = N >> 8;
    const int nwg = gridDim.x;
    const int cpx = nwg >> 3;                       // nwg % 8 == 0 for our shapes
    const int lin = (blockIdx.x & 7) * cpx + (blockIdx.x >> 3);
    const int m0 = (lin / nN) * 256, n0 = (lin % nN) * 256;

    const int tid = threadIdx.x;
    const int w = tid >> 6, l = tid & 63;
    const int wm = w >> 2, wn = w & 3;              // 2 x 4 waves
    const int lg = l >> 4, lc = l & 15;
    const int swz = (lc & 7) << 4;
    const int NT = K >> 6;
    const int HMAX = NT * 4;

    f32x4 acc[2][2][4][2] = {};                     // [mq][nq][mt][nt]

    auto stage = [&](int H) {
        const int tau = H >> 2, h = H & 3;          // h: 0=A0 1=A1 2=B0 3=B1
        bf16* dst = &ldsAB[tau & 1][h >> 1][h & 1][0];
#pragma unroll
        for (int j = 0; j < 2; ++j) {
            int r = w * 8 + j * 64 + (l >> 3);
            int scb = ((l & 7) * 16) ^ ((r & 7) << 4);
            const bf16* g = (h < 2)
                ? A + (size_t)(m0 + (h & 1) * 128 + r) * K + tau * 64 + (scb >> 1)
                : B + (size_t)(n0 + (h & 1) * 128 + r) * K + tau * 64 + (scb >> 1);
            gld16(dst + (w * 8 + j * 64) * 64, g);
        }
    };

    // prologue: tile0 (4 halves) + tile1 half0; wait tile0 (2 loads outstanding)
    stage(0); stage(1); stage(2); stage(3); stage(4);
    SBAR();
    asm volatile("s_waitcnt vmcnt(2)" ::: "memory");
    HWBAR();

    for (int t = 0; t < NT; ++t) {
        const int c = t & 1;
        const char* Ab = (const char*)&ldsAB[c][0][wm][0];
        const char* Bb = (const char*)&ldsAB[c][1][wn >> 1][0];
        const int brow0 = (wn & 1) * 64;
        bf16x8 Af[4][2], Bf[2][2][2];

        // ---- phase 0: (mq0, nq0) — read A(mq0) + B(nq0) ----
#pragma unroll
        for (int mt = 0; mt < 4; ++mt)
#pragma unroll
            for (int ks = 0; ks < 2; ++ks)
                Af[mt][ks] = *(const bf16x8*)(Ab + (mt * 16 + lc) * 128 + ((ks * 64 + lg * 16) ^ swz));
#pragma unroll
        for (int nt = 0; nt < 2; ++nt)
#pragma unroll
            for (int ks = 0; ks < 2; ++ks)
                Bf[0][nt][ks] = *(const bf16x8*)(Bb + (brow0 + nt * 16 + lc) * 128 + ((ks * 64 + lg * 16) ^ swz));
        { int H = 4 * t + 5; if (H < HMAX) stage(H); }
        HWBAR();
        __builtin_amdgcn_s_setprio(1);
#pragma unroll
        for (int mt = 0; mt < 4; ++mt)
#pragma unroll
            for (int nt = 0; nt < 2; ++nt)
#pragma unroll
                for (int ks = 0; ks < 2; ++ks)
                    acc[0][0][mt][nt] = __builtin_amdgcn_mfma_f32_16x16x32_bf16(Af[mt][ks], Bf[0][nt][ks], acc[0][0][mt][nt], 0, 0, 0);
        __builtin_amdgcn_s_setprio(0);
        HWBAR();

        // ---- phase 1: (mq0, nq1) — read B(nq1) ----
#pragma unroll
        for (int nt = 0; nt < 2; ++nt)
#pragma unroll
            for (int ks = 0; ks < 2; ++ks)
                Bf[1][nt][ks] = *(const bf16x8*)(Bb + (brow0 + 32 + nt * 16 + lc) * 128 + ((ks * 64 + lg * 16) ^ swz));
        { int H = 4 * t + 6; if (H < HMAX) stage(H); }
        HWBAR();
        __builtin_amdgcn_s_setprio(1);
#pragma unroll
        for (int mt = 0; mt < 4; ++mt)
#pragma unroll
            for (int nt = 0; nt < 2; ++nt)
#pragma unroll
                for (int ks = 0; ks < 2; ++ks)
                    acc[0][1][mt][nt] = __builtin_amdgcn_mfma_f32_16x16x32_bf16(Af[mt][ks], Bf[1][nt][ks], acc[0][1][mt][nt], 0, 0, 0);
        __builtin_amdgcn_s_setprio(0);
        HWBAR();

        // ---- phase 2: (mq1, nq0) — re-read A(mq1) ----
#pragma unroll
        for (int mt = 0; mt < 4; ++mt)
#pragma unroll
            for (int ks = 0; ks < 2; ++ks)
                Af[mt][ks] = *(const bf16x8*)(Ab + (64 + mt * 16 + lc) * 128 + ((ks * 64 + lg * 16) ^ swz));
        { int H = 4 * t + 7; if (H < HMAX) stage(H); }
        HWBAR();
        __builtin_amdgcn_s_setprio(1);
#pragma unroll
        for (int mt = 0; mt < 4; ++mt)
#pragma unroll
            for (int nt = 0; nt < 2; ++nt)
#pragma unroll
                for (int ks = 0; ks < 2; ++ks)
                    acc[1][0][mt][nt] = __builtin_amdgcn_mfma_f32_16x16x32_bf16(Af[mt][ks], Bf[0][nt][ks], acc[1][0][mt][nt], 0, 0, 0);
        __builtin_amdgcn_s_setprio(0);
        HWBAR();

        // ---- phase 3: (mq1, nq1) — no reads; vmcnt for next tile ----
        { int H = 4 * t + 8; if (H < HMAX) stage(H); }
        HWBAR();
        __builtin_amdgcn_s_setprio(1);
#pragma unroll
        for (int mt = 0; mt < 4; ++mt)
#pragma unroll
            for (int nt = 0; nt < 2; ++nt)
#pragma unroll
                for (int ks = 0; ks < 2; ++ks)
                    acc[1][1][mt][nt] = __builtin_amdgcn_mfma_f32_16x16x32_bf16(Af[mt][ks], Bf[1][nt][ks], acc[1][1][mt][nt], 0, 0, 0);
        __builtin_amdgcn_s_setprio(0);
        SBAR();
        asm volatile("s_waitcnt vmcnt(2)" ::: "memory");  // next tile resident
        HWBAR();
    }

    // ---- epilogue ----
#pragma unroll
    for (int mq = 0; mq < 2; ++mq)
#pragma unroll
        for (int nq = 0; nq < 2; ++nq)
#pragma unroll
            for (int mt = 0; mt < 4; ++mt)
#pragma unroll
                for (int nt = 0; nt < 2; ++nt)
#pragma unroll
                    for (int rr = 0; rr < 4; ++rr) {
                        size_t row = (size_t)m0 + wm * 128 + mq * 64 + mt * 16 + lg * 4 + rr;
                        size_t col = (size_t)n0 + wn * 64 + nq * 32 + nt * 16 + lc;
                        float v = acc[mq][nq][mt][nt][rr];
                        if (OUTF32) ((float*)Cout)[row * N + col] = v;
                        else        ((bf16*)Cout)[row * N + col] = (bf16)v;
                    }
}

// ---------------- Flash attention (causal), LDS-staged ----------------
// Q at QKV col 0, K at col 2048 (row stride 6144); Vt: [B,H,D,S]; O: [B*S,2048].
__global__ __launch_bounds__(256)
void flash_attn(const bf16* __restrict__ QKV, const bf16* __restrict__ Vt,
                bf16* __restrict__ O) {
    __shared__ __align__(16) bf16 Ks[2][64 * 128];   // [key][d], rows 256B
    __shared__ __align__(16) bf16 Vs[2][128 * 64];   // [d][key], rows 128B
    __shared__ __align__(16) bf16 p_lds[4][16 * 64]; // per-wave P, rows 128B

    const int hw = blockIdx.x;
    const int lin = (hw & 7) * 128 + (hw >> 3);
    const int bh = lin >> 5;
    const int qb = 31 - (lin & 31);
    const int b = bh >> 4, h = bh & 15;

    const int tid = threadIdx.x;
    const int w = tid >> 6, l = tid & 63;
    const int lg = l >> 4, lc = l & 15;
    const int q0 = qb * 64 + w * 16;

    auto stageK = [&](int p, int kb) {
#pragma unroll
        for (int c = 0; c < 4; ++c) {
            int r = c * 16 + w * 4 + (l >> 4);
            int scb = ((l & 15) * 16) ^ ((r & 7) << 4);
            const bf16* g = QKV + ((size_t)(b * SEQ + kb * 64 + r)) * QKV_LD + D_MODEL + h * HD + (scb >> 1);
            gld16(&Ks[p][(c * 16 + w * 4) * 128], g);
        }
    };
    auto stageV = [&](int p, int kb) {
#pragma unroll
        for (int c = 0; c < 4; ++c) {
            int r = c * 32 + w * 8 + (l >> 3);
            int scb = ((l & 7) * 16) ^ ((r & 7) << 4);
            const bf16* g = Vt + ((size_t)bh * HD + r) * SEQ + kb * 64 + (scb >> 1);
            gld16(&Vs[p][(c * 32 + w * 8) * 64], g);
        }
    };

    const bf16* qp = QKV + ((size_t)(b * SEQ + q0 + lc)) * QKV_LD + h * HD + lg * 8;
    bf16x8 qf[4];
#pragma unroll
    for (int kc = 0; kc < 4; ++kc) qf[kc] = *(const bf16x8*)(qp + kc * 32);

    f32x4 ctx[8] = {};
    float mrun[4], lrun[4];
#pragma unroll
    for (int r = 0; r < 4; ++r) { mrun[r] = -INFINITY; lrun[r] = 0.f; }

    stageK(0, 0);
    stageV(0, 0);
    int cur = 0;
    const int kswz = (lc & 7) << 4;
    char* pb = (char*)&p_lds[w][0];

    for (int kb = 0; kb <= qb; ++kb) {
        __syncthreads();
        if (kb < qb) { stageK(cur ^ 1, kb + 1); stageV(cur ^ 1, kb + 1); }

        const char* kbp = (const char*)&Ks[cur][0];
        f32x4 sacc[4] = {};
#pragma unroll
        for (int nf = 0; nf < 4; ++nf) {
            int krow = nf * 16 + lc;
#pragma unroll
            for (int kc = 0; kc < 4; ++kc) {
                bf16x8 kf = *(const bf16x8*)(kbp + krow * 256 + ((kc * 64 + lg * 16) ^ kswz));
                sacc[nf] = __builtin_amdgcn_mfma_f32_16x16x32_bf16(qf[kc], kf, sacc[nf], 0, 0, 0);
            }
        }

        if (kb == qb) {
#pragma unroll
            for (int nf = 0; nf < 4; ++nf) {
                int key = kb * 64 + nf * 16 + lc;
#pragma unroll
                for (int r = 0; r < 4; ++r)
                    if (key > q0 + lg * 4 + r) sacc[nf][r] = -INFINITY;
            }
        }

        float scv[4], rs[4];
#pragma unroll
        for (int r = 0; r < 4; ++r) {
            float mx = fmaxf(fmaxf(sacc[0][r], sacc[1][r]), fmaxf(sacc[2][r], sacc[3][r]));
#pragma unroll
            for (int off = 1; off < 16; off <<= 1) mx = fmaxf(mx, __shfl_xor(mx, off));
            float mi = fmaxf(mrun[r], mx);
            scv[r] = __expf(mrun[r] - mi);
            mrun[r] = mi;
            rs[r] = 0.f;
        }
#pragma unroll
        for (int nf = 0; nf < 4; ++nf)
#pragma unroll
            for (int r = 0; r < 4; ++r) {
                float p = __expf(sacc[nf][r] - mrun[r]);
                rs[r] += p;
                int pr = lg * 4 + r;
                int pcb = (nf * 16 + lc) * 2;
                *(bf16*)(pb + pr * 128 + (pcb ^ ((pr & 7) << 4))) = (bf16)p;
            }
#pragma unroll
        for (int r = 0; r < 4; ++r) {
#pragma unroll
            for (int off = 1; off < 16; off <<= 1) rs[r] += __shfl_xor(rs[r], off);
            lrun[r] = lrun[r] * scv[r] + rs[r];
        }
#pragma unroll
        for (int nd = 0; nd < 8; ++nd)
#pragma unroll
            for (int r = 0; r < 4; ++r) ctx[nd][r] *= scv[r];

        asm volatile("s_waitcnt lgkmcnt(0)" ::: "memory");
        bf16x8 pa0 = *(const bf16x8*)(pb + lc * 128 + ((lg * 16) ^ kswz));
        bf16x8 pa1 = *(const bf16x8*)(pb + lc * 128 + ((64 + lg * 16) ^ kswz));

        const char* vb = (const char*)&Vs[cur][0];
#pragma unroll
        for (int nd = 0; nd < 8; ++nd) {
            int vrow = nd * 16 + lc;
#pragma unroll
            for (int k2 = 0; k2 < 2; ++k2) {
                bf16x8 vf = *(const bf16x8*)(vb + vrow * 128 + ((k2 * 64 + lg * 16) ^ kswz));
                ctx[nd] = __builtin_amdgcn_mfma_f32_16x16x32_bf16(k2 ? pa1 : pa0, vf, ctx[nd], 0, 0, 0);
            }
        }
        cur ^= 1;
    }

#pragma unroll
    for (int r = 0; r < 4; ++r) lrun[r] = 1.f / lrun[r];
#pragma unroll
    for (int nd = 0; nd < 8; ++nd)
#pragma unroll
        for (int r = 0; r < 4; ++r)
            O[((size_t)(b * SEQ + q0 + lg * 4 + r)) * D_MODEL + h * HD + nd * 16 + lc] =
                (bf16)(ctx[nd][r] * lrun[r]);
}

// ---------------- launch ----------------
extern "C" void kernel_launch(void* const* d_in, const int* in_sizes, int n_in,
                              void* d_out, int out_size, void* d_ws, size_t ws_size,
                              hipStream_t stream) {
    const float* x  = (const float*)d_in[0];
    const float* Wq = (const float*)d_in[1];
    const float* Wk = (const float*)d_in[2];
    const float* Wv = (const float*)d_in[3];
    const float* Wo = (const float*)d_in[4];

    char* ws = (char*)d_ws;
    bf16* xb   = (bf16*)(ws + 0);            // 16 MB; reused as ctx after QKV GEMM
    bf16* wqkv = (bf16*)(ws + 16777216);     // 24 MB  [6144][2048]
    bf16* wob  = (bf16*)(ws + 41943040);     // 8 MB
    bf16* QKV  = (bf16*)(ws + 50331648);     // 48 MB  [4096][6144]
    bf16* Vtb  = (bf16*)(ws + 100663296);    // 16 MB  [B,H,D,S]
    float* cosd = (float*)(ws + 117440512);
    float* sind = (float*)(ws + 117964800);

    const int NX = BATCH * SEQ * D_MODEL;   // 8388608
    const int NW = D_MODEL * D_MODEL;       // 4194304

    cvt_f32_bf16<<<NX / 1024, 256, 0, stream>>>(x,  xb,  NX);
    cvt_f32_bf16<<<NW / 1024, 256, 0, stream>>>(Wq, wqkv,            NW);
    cvt_f32_bf16<<<NW / 1024, 256, 0, stream>>>(Wk, wqkv + NW,       NW);
    cvt_f32_bf16<<<NW / 1024, 256, 0, stream>>>(Wv, wqkv + 2 * NW,   NW);
    cvt_f32_bf16<<<NW / 1024, 256, 0, stream>>>(Wo, wob,             NW);

    rope_tables_k<<<(SEQ * 64) / 256, 256, 0, stream>>>(cosd, sind);

    // fused QKV projection: [4096,2048] x [6144,2048]^T -> [4096,6144]
    gemm8p<0><<<dim3((QKV_LD / 256) * ((BATCH * SEQ) / 256)), 512, 0, stream>>>(
        xb, wqkv, QKV, BATCH * SEQ, QKV_LD, D_MODEL);

    const float qscale = 0.08838834764831845f;  // 1/sqrt(128)
    rope_apply<<<(BATCH * SEQ * 1024) / 256, 256, 0, stream>>>(QKV,           cosd, sind, qscale, QKV_LD);
    rope_apply<<<(BATCH * SEQ * 1024) / 256, 256, 0, stream>>>(QKV + D_MODEL, cosd, sind, 1.0f,   QKV_LD);

    transpose_v<<<dim3(SEQ / 32, HD / 32, BATCH * NH), 256, 0, stream>>>(QKV + 2 * D_MODEL, Vtb, QKV_LD);

    flash_attn<<<dim3(1024), 256, 0, stream>>>(QKV, Vtb, xb /*ctx*/);

    // output projection: [4096,2048] x [2048,2048]^T -> d_out (f32)
    gemm8p<1><<<dim3((D_MODEL / 256) * ((BATCH * SEQ) / 256)), 512, 0, stream>>>(
        xb, wob, d_out, BATCH * SEQ, D_MODEL, D_MODEL);
}

// Round 5
// 295.957 us; speedup vs baseline: 2.9284x; 1.1800x over previous
//
#include <hip/hip_runtime.h>
#include <hip/hip_bf16.h>
#include <cstdint>
#include <cstddef>

typedef __bf16 bf16;
typedef __bf16 bf16x4 __attribute__((ext_vector_type(4)));
typedef __bf16 bf16x8 __attribute__((ext_vector_type(8)));
typedef float f32x4 __attribute__((ext_vector_type(4)));

#define D_MODEL 2048
#define SEQ     2048
#define NH      16
#define HD      128
#define BATCH   2
#define QKV_LD  6144

#define SBAR()  __builtin_amdgcn_sched_barrier(0)
#define HWBAR() do { SBAR(); __builtin_amdgcn_s_barrier(); SBAR(); } while (0)

// ---------------- async global->LDS 16B ----------------
__device__ __forceinline__ void gld16(void* lds, const void* g) {
    __builtin_amdgcn_global_load_lds(
        (const __attribute__((address_space(1))) unsigned int*)g,
        (__attribute__((address_space(3))) unsigned int*)lds,
        16, 0, 0);
}

// ---------------- fp32 -> bf16 convert ----------------
__global__ __launch_bounds__(256) void cvt_f32_bf16(const float* __restrict__ in,
                                                    bf16* __restrict__ out, int n) {
    int i = (blockIdx.x * 256 + threadIdx.x) * 4;
    if (i < n) {
        float4 v = *(const float4*)(in + i);
        out[i + 0] = (bf16)v.x;
        out[i + 1] = (bf16)v.y;
        out[i + 2] = (bf16)v.z;
        out[i + 3] = (bf16)v.w;
    }
}

// ---------------- RoPE tables (cos/sin, S x 64) ----------------
__global__ __launch_bounds__(256) void rope_tables_k(float* __restrict__ cosd,
                                                     float* __restrict__ sind) {
    int id = blockIdx.x * 256 + threadIdx.x;  // SEQ*64
    int s = id >> 6, d = id & 63;
    float freq = powf(10000.f, -(float)d * (1.f / 64.f));
    float a = (float)s * freq;
    float sn, c;
    sincosf(a, &sn, &c);
    cosd[id] = c;
    sind[id] = sn;
}

// ---------------- RoPE apply (in-place, row stride ld) ----------------
__global__ __launch_bounds__(256) void rope_apply(bf16* __restrict__ T,
                                                  const float* __restrict__ cosd,
                                                  const float* __restrict__ sind,
                                                  float scale, int ld) {
    int id = blockIdx.x * 256 + threadIdx.x;   // B*S*NH*64
    int row = id >> 10;                        // B*S
    int p = id & 1023;
    int h = p >> 6, d = p & 63;
    int s = row & (SEQ - 1);
    size_t base = (size_t)row * ld + h * HD + d;
    float x1 = (float)T[base];
    float x2 = (float)T[base + 64];
    float c = cosd[(s << 6) + d];
    float sn = sind[(s << 6) + d];
    T[base]      = (bf16)((x1 * c - x2 * sn) * scale);
    T[base + 64] = (bf16)((x2 * c + x1 * sn) * scale);
}

// ---------------- V transpose: [B,S,(ld)] head cols -> [B,H,D,S] ----------------
__global__ __launch_bounds__(256) void transpose_v(const bf16* __restrict__ V,
                                                   bf16* __restrict__ Vt, int ld) {
    __shared__ bf16 t[32][33];
    int s0 = blockIdx.x * 32;
    int d0 = blockIdx.y * 32;
    int bh = blockIdx.z;
    int b = bh >> 4, h = bh & 15;
    int tx = threadIdx.x & 31, ty = threadIdx.x >> 5;  // ty 0..7
#pragma unroll
    for (int i = 0; i < 32; i += 8)
        t[ty + i][tx] = V[((size_t)(b * SEQ + s0 + ty + i)) * ld + h * HD + d0 + tx];
    __syncthreads();
#pragma unroll
    for (int i = 0; i < 32; i += 8)
        Vt[((size_t)bh * HD + d0 + ty + i) * SEQ + s0 + tx] = t[tx][ty + i];
}

// ---------------- 256x256 8-phase NT GEMM (unchanged from R2) ----------------
template <int OUTF32>
__global__ __launch_bounds__(512, 2)
void gemm8p(const bf16* __restrict__ A, const bf16* __restrict__ B,
            void* __restrict__ Cout, int M, int N, int K) {
    __shared__ __align__(16) bf16 ldsAB[2][2][2][128 * 64];

    const int nN = N >> 8;
    const int nwg = gridDim.x;
    const int cpx = nwg >> 3;
    const int lin = (blockIdx.x & 7) * cpx + (blockIdx.x >> 3);
    const int m0 = (lin / nN) * 256, n0 = (lin % nN) * 256;

    const int tid = threadIdx.x;
    const int w = tid >> 6, l = tid & 63;
    const int wm = w >> 2, wn = w & 3;
    const int lg = l >> 4, lc = l & 15;
    const int swz = (lc & 7) << 4;
    const int NT = K >> 6;
    const int HMAX = NT * 4;

    f32x4 acc[2][2][4][2] = {};

    auto stage = [&](int H) {
        const int tau = H >> 2, h = H & 3;
        bf16* dst = &ldsAB[tau & 1][h >> 1][h & 1][0];
#pragma unroll
        for (int j = 0; j < 2; ++j) {
            int r = w * 8 + j * 64 + (l >> 3);
            int scb = ((l & 7) * 16) ^ ((r & 7) << 4);
            const bf16* g = (h < 2)
                ? A + (size_t)(m0 + (h & 1) * 128 + r) * K + tau * 64 + (scb >> 1)
                : B + (size_t)(n0 + (h & 1) * 128 + r) * K + tau * 64 + (scb >> 1);
            gld16(dst + (w * 8 + j * 64) * 64, g);
        }
    };

    stage(0); stage(1); stage(2); stage(3); stage(4);
    SBAR();
    asm volatile("s_waitcnt vmcnt(2)" ::: "memory");
    HWBAR();

    for (int t = 0; t < NT; ++t) {
        const int c = t & 1;
        const char* Ab = (const char*)&ldsAB[c][0][wm][0];
        const char* Bb = (const char*)&ldsAB[c][1][wn >> 1][0];
        const int brow0 = (wn & 1) * 64;
        bf16x8 Af[4][2], Bf[2][2][2];

#pragma unroll
        for (int mt = 0; mt < 4; ++mt)
#pragma unroll
            for (int ks = 0; ks < 2; ++ks)
                Af[mt][ks] = *(const bf16x8*)(Ab + (mt * 16 + lc) * 128 + ((ks * 64 + lg * 16) ^ swz));
#pragma unroll
        for (int nt = 0; nt < 2; ++nt)
#pragma unroll
            for (int ks = 0; ks < 2; ++ks)
                Bf[0][nt][ks] = *(const bf16x8*)(Bb + (brow0 + nt * 16 + lc) * 128 + ((ks * 64 + lg * 16) ^ swz));
        { int H = 4 * t + 5; if (H < HMAX) stage(H); }
        HWBAR();
        __builtin_amdgcn_s_setprio(1);
#pragma unroll
        for (int mt = 0; mt < 4; ++mt)
#pragma unroll
            for (int nt = 0; nt < 2; ++nt)
#pragma unroll
                for (int ks = 0; ks < 2; ++ks)
                    acc[0][0][mt][nt] = __builtin_amdgcn_mfma_f32_16x16x32_bf16(Af[mt][ks], Bf[0][nt][ks], acc[0][0][mt][nt], 0, 0, 0);
        __builtin_amdgcn_s_setprio(0);
        HWBAR();

#pragma unroll
        for (int nt = 0; nt < 2; ++nt)
#pragma unroll
            for (int ks = 0; ks < 2; ++ks)
                Bf[1][nt][ks] = *(const bf16x8*)(Bb + (brow0 + 32 + nt * 16 + lc) * 128 + ((ks * 64 + lg * 16) ^ swz));
        { int H = 4 * t + 6; if (H < HMAX) stage(H); }
        HWBAR();
        __builtin_amdgcn_s_setprio(1);
#pragma unroll
        for (int mt = 0; mt < 4; ++mt)
#pragma unroll
            for (int nt = 0; nt < 2; ++nt)
#pragma unroll
                for (int ks = 0; ks < 2; ++ks)
                    acc[0][1][mt][nt] = __builtin_amdgcn_mfma_f32_16x16x32_bf16(Af[mt][ks], Bf[1][nt][ks], acc[0][1][mt][nt], 0, 0, 0);
        __builtin_amdgcn_s_setprio(0);
        HWBAR();

#pragma unroll
        for (int mt = 0; mt < 4; ++mt)
#pragma unroll
            for (int ks = 0; ks < 2; ++ks)
                Af[mt][ks] = *(const bf16x8*)(Ab + (64 + mt * 16 + lc) * 128 + ((ks * 64 + lg * 16) ^ swz));
        { int H = 4 * t + 7; if (H < HMAX) stage(H); }
        HWBAR();
        __builtin_amdgcn_s_setprio(1);
#pragma unroll
        for (int mt = 0; mt < 4; ++mt)
#pragma unroll
            for (int nt = 0; nt < 2; ++nt)
#pragma unroll
                for (int ks = 0; ks < 2; ++ks)
                    acc[1][0][mt][nt] = __builtin_amdgcn_mfma_f32_16x16x32_bf16(Af[mt][ks], Bf[0][nt][ks], acc[1][0][mt][nt], 0, 0, 0);
        __builtin_amdgcn_s_setprio(0);
        HWBAR();

        { int H = 4 * t + 8; if (H < HMAX) stage(H); }
        HWBAR();
        __builtin_amdgcn_s_setprio(1);
#pragma unroll
        for (int mt = 0; mt < 4; ++mt)
#pragma unroll
            for (int nt = 0; nt < 2; ++nt)
#pragma unroll
                for (int ks = 0; ks < 2; ++ks)
                    acc[1][1][mt][nt] = __builtin_amdgcn_mfma_f32_16x16x32_bf16(Af[mt][ks], Bf[1][nt][ks], acc[1][1][mt][nt], 0, 0, 0);
        __builtin_amdgcn_s_setprio(0);
        SBAR();
        asm volatile("s_waitcnt vmcnt(2)" ::: "memory");
        HWBAR();
    }

#pragma unroll
    for (int mq = 0; mq < 2; ++mq)
#pragma unroll
        for (int nq = 0; nq < 2; ++nq)
#pragma unroll
            for (int mt = 0; mt < 4; ++mt)
#pragma unroll
                for (int nt = 0; nt < 2; ++nt)
#pragma unroll
                    for (int rr = 0; rr < 4; ++rr) {
                        size_t row = (size_t)m0 + wm * 128 + mq * 64 + mt * 16 + lg * 4 + rr;
                        size_t col = (size_t)n0 + wn * 64 + nq * 32 + nt * 16 + lc;
                        float v = acc[mq][nq][mt][nt][rr];
                        if (OUTF32) ((float*)Cout)[row * N + col] = v;
                        else        ((bf16*)Cout)[row * N + col] = (bf16)v;
                    }
}

// ---------------- Flash attention (causal), paired tiles + swapped QK^T ----
// 512 blocks: (bh, j) pairs q-tiles {31-j, j} -> 33 iterations each (balanced).
// Swapped MFMA: st = mfma(kf, qf) so lane (lg,lc) holds S[q=lc][16 keys]
// -> row softmax is in-lane(16) + 2 shfl_xor; P written as packed 8B stores.
__global__ __launch_bounds__(256)
void flash_attn(const bf16* __restrict__ QKV, const bf16* __restrict__ Vt,
                bf16* __restrict__ O) {
    __shared__ __align__(16) bf16 Ks[2][64 * 128];   // [key][d], rows 256B
    __shared__ __align__(16) bf16 Vs[2][128 * 64];   // [d][key], rows 128B
    __shared__ __align__(16) bf16 p_lds[4][16 * 64]; // per-wave P[q][key], rows 128B

    const int bid = blockIdx.x;                   // 512
    const int lin = (bid & 7) * 64 + (bid >> 3);  // XCD-chunked
    const int bh = lin >> 4;
    const int jj = lin & 15;
    const int b = bh >> 4, h = bh & 15;

    const int tid = threadIdx.x;
    const int w = tid >> 6, l = tid & 63;
    const int lg = l >> 4, lc = l & 15;
    const int kswz = (lc & 7) << 4;
    char* pb = (char*)&p_lds[w][0];

    auto stageK = [&](int p, int kb) {
#pragma unroll
        for (int c = 0; c < 4; ++c) {
            int r = c * 16 + w * 4 + (l >> 4);
            int scb = ((l & 15) * 16) ^ ((r & 7) << 4);
            const bf16* g = QKV + ((size_t)(b * SEQ + kb * 64 + r)) * QKV_LD + D_MODEL + h * HD + (scb >> 1);
            gld16(&Ks[p][(c * 16 + w * 4) * 128], g);
        }
    };
    auto stageV = [&](int p, int kb) {
#pragma unroll
        for (int c = 0; c < 4; ++c) {
            int r = c * 32 + w * 8 + (l >> 3);
            int scb = ((l & 7) * 16) ^ ((r & 7) << 4);
            const bf16* g = Vt + ((size_t)bh * HD + r) * SEQ + kb * 64 + (scb >> 1);
            gld16(&Vs[p][(c * 32 + w * 8) * 64], g);
        }
    };

    int cur = 0;
#pragma unroll 1
    for (int ti = 0; ti < 2; ++ti) {
        const int qt = ti ? jj : (31 - jj);       // long tile first
        const int q0 = qt * 64 + w * 16;

        const bf16* qp = QKV + ((size_t)(b * SEQ + q0 + lc)) * QKV_LD + h * HD + lg * 8;
        bf16x8 qf[4];
#pragma unroll
        for (int kc = 0; kc < 4; ++kc) qf[kc] = *(const bf16x8*)(qp + kc * 32);

        f32x4 ctx[8] = {};
        float m_s = -INFINITY, l_s = 0.f;

        stageK(cur, 0);
        stageV(cur, 0);

        for (int kb = 0; kb <= qt; ++kb) {
            __syncthreads();  // buf[cur] staged (vmcnt drained); prior reads done
            if (kb < qt) { stageK(cur ^ 1, kb + 1); stageV(cur ^ 1, kb + 1); }

            // ---- S^T-fragment QK^T: st[nf][r] = S[q=q0+lc][key=kb*64+nf*16+lg*4+r]
            const char* kbp = (const char*)&Ks[cur][0];
            f32x4 st[4] = {};
#pragma unroll
            for (int nf = 0; nf < 4; ++nf) {
                int krow = nf * 16 + lc;
#pragma unroll
                for (int kc = 0; kc < 4; ++kc) {
                    bf16x8 kf = *(const bf16x8*)(kbp + krow * 256 + ((kc * 64 + lg * 16) ^ kswz));
                    st[nf] = __builtin_amdgcn_mfma_f32_16x16x32_bf16(kf, qf[kc], st[nf], 0, 0, 0);
                }
            }

            if (kb == qt) {  // causal mask: key > q
                int q = q0 + lc;
#pragma unroll
                for (int nf = 0; nf < 4; ++nf) {
                    int key = kb * 64 + nf * 16 + lg * 4;
#pragma unroll
                    for (int r = 0; r < 4; ++r)
                        if (key + r > q) st[nf][r] = -INFINITY;
                }
            }

            // ---- online softmax for q=q0+lc: in-lane 16 + 2 shfl stages ----
            float mx = -INFINITY;
#pragma unroll
            for (int nf = 0; nf < 4; ++nf)
#pragma unroll
                for (int r = 0; r < 4; ++r) mx = fmaxf(mx, st[nf][r]);
            mx = fmaxf(mx, __shfl_xor(mx, 16));
            mx = fmaxf(mx, __shfl_xor(mx, 32));
            float mi = fmaxf(m_s, mx);
            float scv = __expf(m_s - mi);
            m_s = mi;

            float rs = 0.f;
#pragma unroll
            for (int nf = 0; nf < 4; ++nf) {
                float p0 = __expf(st[nf][0] - mi);
                float p1 = __expf(st[nf][1] - mi);
                float p2 = __expf(st[nf][2] - mi);
                float p3 = __expf(st[nf][3] - mi);
                rs += (p0 + p1) + (p2 + p3);
                bf16x4 pv = { (bf16)p0, (bf16)p1, (bf16)p2, (bf16)p3 };
                *(bf16x4*)(pb + lc * 128 + ((nf * 32 + lg * 8) ^ kswz)) = pv;
            }
            rs += __shfl_xor(rs, 16);
            rs += __shfl_xor(rs, 32);
            l_s = l_s * scv + rs;

            // broadcast scv to ctx rows (q_local = lg*4+r lives in lane lg*4+r)
            float scvr[4];
#pragma unroll
            for (int r = 0; r < 4; ++r) scvr[r] = __shfl(scv, lg * 4 + r);
#pragma unroll
            for (int nd = 0; nd < 8; ++nd)
#pragma unroll
                for (int r = 0; r < 4; ++r) ctx[nd][r] *= scvr[r];

            // cross-lane P writes -> visible to this wave's reads
            asm volatile("s_waitcnt lgkmcnt(0)" ::: "memory");
            SBAR();
            bf16x8 pa0 = *(const bf16x8*)(pb + lc * 128 + ((lg * 16) ^ kswz));
            bf16x8 pa1 = *(const bf16x8*)(pb + lc * 128 + ((64 + lg * 16) ^ kswz));

            // ---- ctx += P V ----
            const char* vb = (const char*)&Vs[cur][0];
#pragma unroll
            for (int nd = 0; nd < 8; ++nd) {
                int vrow = nd * 16 + lc;
#pragma unroll
                for (int k2 = 0; k2 < 2; ++k2) {
                    bf16x8 vf = *(const bf16x8*)(vb + vrow * 128 + ((k2 * 64 + lg * 16) ^ kswz));
                    ctx[nd] = __builtin_amdgcn_mfma_f32_16x16x32_bf16(k2 ? pa1 : pa0, vf, ctx[nd], 0, 0, 0);
                }
            }
            cur ^= 1;
        }

        float lr[4];
#pragma unroll
        for (int r = 0; r < 4; ++r) lr[r] = 1.f / __shfl(l_s, lg * 4 + r);
#pragma unroll
        for (int nd = 0; nd < 8; ++nd)
#pragma unroll
            for (int r = 0; r < 4; ++r)
                O[((size_t)(b * SEQ + q0 + lg * 4 + r)) * D_MODEL + h * HD + nd * 16 + lc] =
                    (bf16)(ctx[nd][r] * lr[r]);
    }
}

// ---------------- launch ----------------
extern "C" void kernel_launch(void* const* d_in, const int* in_sizes, int n_in,
                              void* d_out, int out_size, void* d_ws, size_t ws_size,
                              hipStream_t stream) {
    const float* x  = (const float*)d_in[0];
    const float* Wq = (const float*)d_in[1];
    const float* Wk = (const float*)d_in[2];
    const float* Wv = (const float*)d_in[3];
    const float* Wo = (const float*)d_in[4];

    char* ws = (char*)d_ws;
    bf16* xb   = (bf16*)(ws + 0);            // 16 MB; reused as ctx after QKV GEMM
    bf16* wqkv = (bf16*)(ws + 16777216);     // 24 MB  [6144][2048]
    bf16* wob  = (bf16*)(ws + 41943040);     // 8 MB
    bf16* QKV  = (bf16*)(ws + 50331648);     // 48 MB  [4096][6144]
    bf16* Vtb  = (bf16*)(ws + 100663296);    // 16 MB  [B,H,D,S]
    float* cosd = (float*)(ws + 117440512);
    float* sind = (float*)(ws + 117964800);

    const int NX = BATCH * SEQ * D_MODEL;   // 8388608
    const int NW = D_MODEL * D_MODEL;       // 4194304

    cvt_f32_bf16<<<NX / 1024, 256, 0, stream>>>(x,  xb,  NX);
    cvt_f32_bf16<<<NW / 1024, 256, 0, stream>>>(Wq, wqkv,            NW);
    cvt_f32_bf16<<<NW / 1024, 256, 0, stream>>>(Wk, wqkv + NW,       NW);
    cvt_f32_bf16<<<NW / 1024, 256, 0, stream>>>(Wv, wqkv + 2 * NW,   NW);
    cvt_f32_bf16<<<NW / 1024, 256, 0, stream>>>(Wo, wob,             NW);

    rope_tables_k<<<(SEQ * 64) / 256, 256, 0, stream>>>(cosd, sind);

    // fused QKV projection: [4096,2048] x [6144,2048]^T -> [4096,6144]
    gemm8p<0><<<dim3((QKV_LD / 256) * ((BATCH * SEQ) / 256)), 512, 0, stream>>>(
        xb, wqkv, QKV, BATCH * SEQ, QKV_LD, D_MODEL);

    const float qscale = 0.08838834764831845f;  // 1/sqrt(128)
    rope_apply<<<(BATCH * SEQ * 1024) / 256, 256, 0, stream>>>(QKV,           cosd, sind, qscale, QKV_LD);
    rope_apply<<<(BATCH * SEQ * 1024) / 256, 256, 0, stream>>>(QKV + D_MODEL, cosd, sind, 1.0f,   QKV_LD);

    transpose_v<<<dim3(SEQ / 32, HD / 32, BATCH * NH), 256, 0, stream>>>(QKV + 2 * D_MODEL, Vtb, QKV_LD);

    flash_attn<<<dim3(512), 256, 0, stream>>>(QKV, Vtb, xb /*ctx*/);

    // output projection: [4096,2048] x [2048,2048]^T -> d_out (f32)
    gemm8p<1><<<dim3((D_MODEL / 256) * ((BATCH * SEQ) / 256)), 512, 0, stream>>>(
        xb, wob, d_out, BATCH * SEQ, D_MODEL, D_MODEL);
}